// Round 1
// baseline (220.105 us; speedup 1.0000x reference)
//
#include <hip/hip_runtime.h>
#include <hip/hip_bf16.h>
#include <stdint.h>

// Problem constants (fixed workload):
//   x:            [B=32, L=4096, D=768] f32 (only shape/dtype used)
//   topic_vectors:[T=2048, D=768] f32
//   out:          [B, L, T] f32 -- 1 GiB, broadcast over B of a [L,T] 0/1 map.
// top_k(softmax(tv), 16) indices == top_k(tv, 16) indices (softmax monotone),
// values are in [0, D) so `% L` is identity -> only rows l < 768 can be 1.

#define B_DIM    32
#define L_DIM    4096
#define D_DIM    768
#define T_TOPICS 2048
#define K_TOP    16

#define WORDS_PER_ROW (T_TOPICS / 32)            // 64 u32 words of topic-bits per l-row
#define BITMAP_WORDS  (D_DIM * WORDS_PER_ROW)    // 49152 words = 192 KiB

__global__ void zero_bitmap_kernel(uint32_t* __restrict__ bm) {
    int i = blockIdx.x * blockDim.x + threadIdx.x;
    if (i < BITMAP_WORDS) bm[i] = 0u;
}

// One wave (64 lanes) per topic. Each lane holds 12 of the 768 values.
// 16 iterations of wave-argmax (tie -> smaller index), knock out winner,
// lane 0 sets bit (l=idx, t=topic) in the [D_DIM][T_TOPICS] bitmap.
__global__ void topk_kernel(const float* __restrict__ tv, uint32_t* __restrict__ bm) {
    const int t    = blockIdx.x;        // topic id
    const int lane = threadIdx.x;       // 0..63
    const float* __restrict__ row = tv + (size_t)t * D_DIM;

    float v[D_DIM / 64];                // 12 values, idx = lane + j*64 (coalesced)
    #pragma unroll
    for (int j = 0; j < D_DIM / 64; ++j) v[j] = row[lane + j * 64];

    for (int k = 0; k < K_TOP; ++k) {
        // local argmax; ascending j + strict '>' keeps the smallest index on ties
        float bv = v[0];
        int   bj = 0;
        #pragma unroll
        for (int j = 1; j < D_DIM / 64; ++j) {
            if (v[j] > bv) { bv = v[j]; bj = j; }
        }
        float cv = bv;
        int   ci = lane + bj * 64;
        // wave butterfly argmax; tie -> smaller global index (matches jax top_k)
        #pragma unroll
        for (int off = 32; off > 0; off >>= 1) {
            float ov = __shfl_xor(cv, off);
            int   oi = __shfl_xor(ci, off);
            if (ov > cv || (ov == cv && oi < ci)) { cv = ov; ci = oi; }
        }
        // all lanes agree on winner ci; owner removes it
        if ((ci & 63) == lane) v[ci >> 6] = -INFINITY;
        if (lane == 0) {
            atomicOr(&bm[ci * WORDS_PER_ROW + (t >> 5)], 1u << (t & 31));
        }
    }
}

// Write the full [B][L][T] output as float4 (16B/lane), grid-stride.
// q indexes float4s: t4 = q & 511 (T/4=512), l = (q>>9) & 4095, b = q>>21.
// Value depends only on (l, t); bitmap reads are tiny and cache-resident.
__global__ void fill_kernel(const uint32_t* __restrict__ bm, float4* __restrict__ out) {
    const unsigned total  = (unsigned)B_DIM * L_DIM * (T_TOPICS / 4);   // 67,108,864
    const unsigned stride = gridDim.x * blockDim.x;
    for (unsigned q = blockIdx.x * blockDim.x + threadIdx.x; q < total; q += stride) {
        const int t4 = (int)(q & (T_TOPICS / 4 - 1));       // 0..511
        const int l  = (int)((q >> 9) & (L_DIM - 1));       // 0..4095
        uint32_t w = 0u;
        if (l < D_DIM) w = bm[l * WORDS_PER_ROW + (t4 >> 3)];
        const int sh = (t4 & 7) * 4;                        // bit offset of t within word
        float4 val;
        val.x = ((w >> (sh + 0)) & 1u) ? 1.0f : 0.0f;
        val.y = ((w >> (sh + 1)) & 1u) ? 1.0f : 0.0f;
        val.z = ((w >> (sh + 2)) & 1u) ? 1.0f : 0.0f;
        val.w = ((w >> (sh + 3)) & 1u) ? 1.0f : 0.0f;
        out[q] = val;
    }
}

extern "C" void kernel_launch(void* const* d_in, const int* in_sizes, int n_in,
                              void* d_out, int out_size, void* d_ws, size_t ws_size,
                              hipStream_t stream) {
    const float* tv  = (const float*)d_in[1];   // topic_vectors [T, D]
    float*       out = (float*)d_out;           // [B, L, T] f32
    uint32_t*    bm  = (uint32_t*)d_ws;         // 192 KiB bitmap

    hipLaunchKernelGGL(zero_bitmap_kernel,
                       dim3((BITMAP_WORDS + 255) / 256), dim3(256), 0, stream, bm);
    hipLaunchKernelGGL(topk_kernel,
                       dim3(T_TOPICS), dim3(64), 0, stream, tv, bm);
    hipLaunchKernelGGL(fill_kernel,
                       dim3(2048), dim3(256), 0, stream, bm, (float4*)out);
}